// Round 11
// baseline (91.480 us; speedup 1.0000x reference)
//
#include <hip/hip_runtime.h>
#include <math.h>

#define KMASK 0xFFFF8000u
#define IMASK 0x7FFFu

__device__ __forceinline__ float wave_reduce_sum(float v) {
    #pragma unroll
    for (int off = 32; off >= 1; off >>= 1) v += __shfl_xor(v, off, 64);
    return v;
}

__device__ __forceinline__ unsigned wave_min_u32(unsigned v) {
    #pragma unroll
    for (int off = 32; off >= 1; off >>= 1) {
        unsigned o = (unsigned)__shfl_xor((int)v, off, 64);
        v = (o < v) ? o : v;
    }
    return v;
}

// reductions over aligned 16-lane group (xor 8,4,2,1 stays in-group)
__device__ __forceinline__ unsigned gmin16(unsigned v) {
    #pragma unroll
    for (int off = 8; off >= 1; off >>= 1) {
        unsigned o = (unsigned)__shfl_xor((int)v, off, 64);
        v = (o < v) ? o : v;
    }
    return v;
}
__device__ __forceinline__ float gsum16(float v) {
    #pragma unroll
    for (int off = 8; off >= 1; off >>= 1) v += __shfl_xor(v, off, 64);
    return v;
}

// sorted ascending insert of packed key into 4-element list
__device__ __forceinline__ void insert4u(unsigned k, unsigned (&b)[4]) {
    const bool c0 = k < b[0], c1 = k < b[1], c2 = k < b[2], c3 = k < b[3];
    b[3] = c2 ? b[2] : (c3 ? k : b[3]);
    b[2] = c1 ? b[1] : (c2 ? k : b[2]);
    b[1] = c0 ? b[0] : (c1 ? k : b[1]);
    b[0] = c0 ? k : b[0];
}

__device__ __forceinline__ int cell_of(float x, int G) {
    int c = (int)(x * (float)G);
    return (c < 0) ? 0 : ((c >= G) ? G - 1 : c);
}

__device__ __forceinline__ float dot2(float2 a, float2 b) {
    return fmaf(a.y, b.y, a.x * b.x);
}

// ================= build: one block per direction, grid in LDS =================

__global__ __launch_bounds__(1024)
void build_grids(const float* __restrict__ cA, int nA, int GA, int* __restrict__ stA,
                 float4* __restrict__ soA, int* __restrict__ siA,
                 const float* __restrict__ cB, int nB, int GB, int* __restrict__ stB,
                 float4* __restrict__ soB, int* __restrict__ siB,
                 float* __restrict__ part)
{
    extern __shared__ int lds[];
    const bool b0 = (blockIdx.x == 0);
    const float* c = b0 ? cA : cB;
    const int    n = b0 ? nA : nB;
    const int    G = b0 ? GA : GB;
    int*        st = b0 ? stA : stB;
    float4*     so = b0 ? soA : soB;
    int*        si = b0 ? siA : siB;
    const int   G3 = G * G * G;
    const int    t = threadIdx.x;
    int* cnt = lds;            // G3+1 entries
    int* scr = lds + G3 + 1;   // 1024 entries

    for (int i = t; i <= G3; i += 1024) cnt[i] = 0;
    if (b0 && t < 64) part[t] = 0.0f;
    __syncthreads();

    for (int p = t; p < n; p += 1024) {
        const int cx = cell_of(c[3*p], G), cy = cell_of(c[3*p+1], G), cz = cell_of(c[3*p+2], G);
        atomicAdd(&cnt[(cz * G + cy) * G + cx + 1], 1);
    }
    __syncthreads();

    const int len = G3 + 1;
    const int chunk = (len + 1023) >> 10;
    const int lo = t * chunk;
    const int hi = (lo + chunk < len) ? (lo + chunk) : len;
    int sum = 0;
    for (int i = lo; i < hi; ++i) sum += cnt[i];
    scr[t] = sum;
    __syncthreads();
    for (int d = 1; d < 1024; d <<= 1) {
        const int v = (t >= d) ? scr[t - d] : 0;
        __syncthreads();
        scr[t] += v;
        __syncthreads();
    }
    int run = (t > 0) ? scr[t - 1] : 0;
    for (int i = lo; i < hi; ++i) {
        run += cnt[i];
        cnt[i] = run;
        st[i] = run;
    }
    __syncthreads();

    for (int p = t; p < n; p += 1024) {
        const float x = c[3*p], y = c[3*p+1], z = c[3*p+2];
        const int cx = cell_of(x, G), cy = cell_of(y, G), cz = cell_of(z, G);
        const int pos = atomicAdd(&cnt[(cz * G + cy) * G + cx], 1);
        so[pos] = make_float4(x, y, z, x*x + y*y + z*z);
        si[pos] = p;
    }
}

// ============= fused grid KNN + loss =============
// 16 lanes per query. Fast path: fully-unrolled 3x3 row-range prefetch.
// Rare non-converged queries use the generic expanding-box loop from s=2.
// Feature phase: all loads issued independently, then reductions.

__global__ __launch_bounds__(256)
void knnloss(const float* __restrict__ ci, const float* __restrict__ fi, int Ni,
             const float* __restrict__ cj, const float* __restrict__ fj, int Nj,
             const float4* __restrict__ soA, const int* __restrict__ stA,
             const int* __restrict__ siA, int GA,
             const float4* __restrict__ soB, const int* __restrict__ stB,
             const int* __restrict__ siB, int GB,
             float sc0, float sc1, float* __restrict__ part)
{
    const int sub = threadIdx.x & 15;
    const int qid = (blockIdx.x * 256 + threadIdx.x) >> 4;
    float acc = 0.0f;

    if (qid < Ni + Nj) {
        const bool d0 = (qid < Ni);
        const int p = d0 ? qid : qid - Ni;
        const float*  cq = d0 ? ci  : cj;
        const float4* so = d0 ? soA : soB;
        const int*    st = d0 ? stA : stB;
        const int*    si = d0 ? siA : siB;
        const int      G = d0 ? GA  : GB;
        const int     nd = d0 ? Nj  : Ni;
        const float* fqp = (d0 ? fi : fj) + (size_t)p * 96;
        const float*  fd = d0 ? fj : fi;
        const float scale = d0 ? sc0 : sc1;

        // hoisted: q-feature fragment (independent of the KNN chain)
        const float2* q2 = (const float2*)fqp;
        const float2 qa = q2[3*sub], qb = q2[3*sub+1], qc = q2[3*sub+2];

        const float qx = cq[3*p], qy = cq[3*p+1], qz = cq[3*p+2];
        const float h = 1.0f / (float)G;
        const int cx = cell_of(qx, G), cy = cell_of(qy, G), cz = cell_of(qz, G);
        const float qq  = qx*qx + qy*qy + qz*qz;
        const float m2x = -2.0f*qx, m2y = -2.0f*qy, m2z = -2.0f*qz;
        unsigned mk[4];

        // ---------- fast path: s = 1, 3x3 rows prefetched ----------
        {
            const int x0 = max(cx - 1, 0), x1 = min(cx + 1, G - 1);
            int csr[9], cer[9];
            #pragma unroll
            for (int dz = 0; dz < 3; ++dz) {
                #pragma unroll
                for (int dy = 0; dy < 3; ++dy) {
                    const int zz = cz + dz - 1, yy = cy + dy - 1;
                    const bool v = ((unsigned)zz < (unsigned)G) & ((unsigned)yy < (unsigned)G);
                    const int rb = v ? (zz * G + yy) * G : 0;
                    csr[dz*3+dy] = v ? st[rb + x0] : 0;
                    cer[dz*3+dy] = v ? st[rb + x1 + 1] : 0;
                }
            }
            unsigned bk[4] = {~0u, ~0u, ~0u, ~0u};
            #pragma unroll
            for (int r = 0; r < 9; ++r) {
                for (int cc = csr[r] + sub; cc < cer[r]; cc += 16) {
                    const float4 P = so[cc];
                    const float d2 =
                        fmaf(P.z, m2z, fmaf(P.y, m2y, fmaf(P.x, m2x, P.w))) + qq;
                    const unsigned k =
                        (__float_as_uint(fmaxf(d2, 0.0f)) & KMASK) | (unsigned)cc;
                    insert4u(k, bk);
                }
            }
            unsigned t0 = bk[0], t1 = bk[1], t2 = bk[2], t3 = bk[3];
            #pragma unroll
            for (int r = 0; r < 4; ++r) {
                const unsigned m = gmin16(t0);
                mk[r] = m;
                const bool win = (t0 == m);
                t0 = win ? t1 : t0;
                t1 = win ? t2 : t1;
                t2 = win ? t3 : t2;
                t3 = win ? ~0u : t3;
            }
            const int y0 = max(cy - 1, 0), y1 = min(cy + 1, G - 1);
            const int z0 = max(cz - 1, 0), z1 = min(cz + 1, G - 1);
            float margin = 3.0e38f;
            if (x0 > 0)     margin = fminf(margin, qx - (float)x0 * h);
            if (x1 < G - 1) margin = fminf(margin, (float)(x1 + 1) * h - qx);
            if (y0 > 0)     margin = fminf(margin, qy - (float)y0 * h);
            if (y1 < G - 1) margin = fminf(margin, (float)(y1 + 1) * h - qy);
            if (z0 > 0)     margin = fminf(margin, qz - (float)z0 * h);
            if (z1 < G - 1) margin = fminf(margin, (float)(z1 + 1) * h - qz);
            const bool covered = (margin > 1.0e37f);
            const float kd = __uint_as_float(mk[3] & KMASK);
            const bool ok = covered || (kd * 1.01f <= margin * margin);

            // ---------- slow path (rare): expanding box from s = 2 ----------
            if (!ok) {
                for (int s = 2; ; ++s) {
                    const int sx0 = max(cx - s, 0), sx1 = min(cx + s, G - 1);
                    const int sy0 = max(cy - s, 0), sy1 = min(cy + s, G - 1);
                    const int sz0 = max(cz - s, 0), sz1 = min(cz + s, G - 1);
                    unsigned b2[4] = {~0u, ~0u, ~0u, ~0u};
                    for (int z = sz0; z <= sz1; ++z) {
                        for (int y = sy0; y <= sy1; ++y) {
                            const int rb = (z * G + y) * G;
                            const int cs = st[rb + sx0];
                            const int ce = st[rb + sx1 + 1];
                            for (int cc = cs + sub; cc < ce; cc += 16) {
                                const float4 P = so[cc];
                                const float d2 =
                                    fmaf(P.z, m2z, fmaf(P.y, m2y, fmaf(P.x, m2x, P.w))) + qq;
                                const unsigned k =
                                    (__float_as_uint(fmaxf(d2, 0.0f)) & KMASK) | (unsigned)cc;
                                insert4u(k, b2);
                            }
                        }
                    }
                    unsigned u0 = b2[0], u1 = b2[1], u2 = b2[2], u3 = b2[3];
                    #pragma unroll
                    for (int r = 0; r < 4; ++r) {
                        const unsigned m = gmin16(u0);
                        mk[r] = m;
                        const bool win = (u0 == m);
                        u0 = win ? u1 : u0;
                        u1 = win ? u2 : u1;
                        u2 = win ? u3 : u2;
                        u3 = win ? ~0u : u3;
                    }
                    float mg = 3.0e38f;
                    if (sx0 > 0)     mg = fminf(mg, qx - (float)sx0 * h);
                    if (sx1 < G - 1) mg = fminf(mg, (float)(sx1 + 1) * h - qx);
                    if (sy0 > 0)     mg = fminf(mg, qy - (float)sy0 * h);
                    if (sy1 < G - 1) mg = fminf(mg, (float)(sy1 + 1) * h - qy);
                    if (sz0 > 0)     mg = fminf(mg, qz - (float)sz0 * h);
                    if (sz1 < G - 1) mg = fminf(mg, (float)(sz1 + 1) * h - qz);
                    const bool cov = (mg > 1.0e37f);
                    const float k2 = __uint_as_float(mk[3] & KMASK);
                    if (cov || (k2 * 1.01f <= mg * mg)) break;
                }
            }
        }

        // ---------- feature phase: all loads issued, then reductions ----------
        const int nm1 = nd - 1;
        const int i0 = si[min((int)(mk[0] & IMASK), nm1)];
        const int i1 = si[min((int)(mk[1] & IMASK), nm1)];
        const int i2 = si[min((int)(mk[2] & IMASK), nm1)];
        const int i3 = si[min((int)(mk[3] & IMASK), nm1)];

        const float2* f0 = (const float2*)(fd + (size_t)i0 * 96);
        const float2* f1 = (const float2*)(fd + (size_t)i1 * 96);
        const float2* f2 = (const float2*)(fd + (size_t)i2 * 96);
        const float2* f3 = (const float2*)(fd + (size_t)i3 * 96);
        const float2 a0 = f0[3*sub], b0 = f0[3*sub+1], c0 = f0[3*sub+2];
        const float2 a1 = f1[3*sub], b1 = f1[3*sub+1], c1 = f1[3*sub+2];
        const float2 a2 = f2[3*sub], b2 = f2[3*sub+1], c2 = f2[3*sub+2];
        const float2 a3 = f3[3*sub], b3 = f3[3*sub+1], c3 = f3[3*sub+2];

        const float ssq = gsum16(dot2(qa,qa) + dot2(qb,qb) + dot2(qc,qc));

        float sim[4];
        {
            const float dv = gsum16(dot2(qa,a0) + dot2(qb,b0) + dot2(qc,c0));
            const float sd = gsum16(dot2(a0,a0) + dot2(b0,b0) + dot2(c0,c0));
            sim[0] = dv * rsqrtf(fmaxf(ssq, 1e-24f) * fmaxf(sd, 1e-24f)) * 10.0f;
        }
        {
            const float dv = gsum16(dot2(qa,a1) + dot2(qb,b1) + dot2(qc,c1));
            const float sd = gsum16(dot2(a1,a1) + dot2(b1,b1) + dot2(c1,c1));
            sim[1] = dv * rsqrtf(fmaxf(ssq, 1e-24f) * fmaxf(sd, 1e-24f)) * 10.0f;
        }
        {
            const float dv = gsum16(dot2(qa,a2) + dot2(qb,b2) + dot2(qc,c2));
            const float sd = gsum16(dot2(a2,a2) + dot2(b2,b2) + dot2(c2,c2));
            sim[2] = dv * rsqrtf(fmaxf(ssq, 1e-24f) * fmaxf(sd, 1e-24f)) * 10.0f;
        }
        {
            const float dv = gsum16(dot2(qa,a3) + dot2(qb,b3) + dot2(qc,c3));
            const float sd = gsum16(dot2(a3,a3) + dot2(b3,b3) + dot2(c3,c3));
            sim[3] = dv * rsqrtf(fmaxf(ssq, 1e-24f) * fmaxf(sd, 1e-24f)) * 10.0f;
        }

        const float m = fmaxf(fmaxf(sim[0], sim[1]), fmaxf(sim[2], sim[3]));
        const float e0 = __expf(sim[0] - m), e1 = __expf(sim[1] - m);
        const float e2 = __expf(sim[2] - m), e3 = __expf(sim[3] - m);
        const float ssum = e0 + e1 + e2 + e3;
        const float inv = 1.0f / ssum;
        const float p2 = (e0*e0 + e1*e1 + e2*e2 + e3*e3) * inv * inv;
        if (sub == 0) acc = -__logf(p2 + 1e-12f) * scale;
    }

    acc = wave_reduce_sum(acc);
    if ((threadIdx.x & 63) == 0) atomicAdd(&part[blockIdx.x & 63], acc);
}

__global__ __launch_bounds__(64)
void final_sum(const float* __restrict__ partial, float* __restrict__ out) {
    float v = partial[threadIdx.x];
    v = wave_reduce_sum(v);
    if (threadIdx.x == 0) out[0] = v;
}

// ============================ brute fallback ============================

#define WPB 4
template<int QPW>
__device__ __forceinline__ void brute_dir(
    const float* __restrict__ cq, const float* __restrict__ fq, int Nq,
    const float* __restrict__ cd, const float* __restrict__ fd, int Nd,
    float scale, float* __restrict__ out, int blk)
{
    const int lane = threadIdx.x & 63;
    const int widx = threadIdx.x >> 6;
    int qbase = (blk * WPB + widx) * QPW;
    if (qbase >= Nq) return;
    qbase = __builtin_amdgcn_readfirstlane(qbase);

    float qx[QPW], qy[QPW], qz[QPW];
    #pragma unroll
    for (int q = 0; q < QPW; ++q) {
        const int qi = (qbase + q < Nq) ? (qbase + q) : (Nq - 1);
        qx[q] = cq[qi*3]; qy[q] = cq[qi*3+1]; qz[q] = cq[qi*3+2];
    }
    unsigned bk[QPW][4];
    #pragma unroll
    for (int q = 0; q < QPW; ++q) {
        #pragma unroll
        for (int k = 0; k < 4; ++k) bk[q][k] = ~0u;
    }
    for (int base = 0; base < Nd; base += 64) {
        const int p = base + lane;
        const int cp = (p < Nd) ? p : (Nd - 1);
        const float px = cd[cp*3], py = cd[cp*3+1], pz = cd[cp*3+2];
        #pragma unroll
        for (int q = 0; q < QPW; ++q) {
            const float dx = px - qx[q], dy = py - qy[q], dz = pz - qz[q];
            const float d2 = dx*dx + dy*dy + dz*dz;
            unsigned k = (__float_as_uint(d2) & KMASK) | (unsigned)p;
            if (p >= Nd) k = ~0u;
            insert4u(k, bk[q]);
        }
    }
    float wacc = 0.0f;
    #pragma unroll
    for (int q = 0; q < QPW; ++q) {
        if (qbase + q >= Nq) break;
        unsigned t0 = bk[q][0], t1 = bk[q][1], t2 = bk[q][2], t3 = bk[q][3];
        int ni_[4];
        #pragma unroll
        for (int k = 0; k < 4; ++k) {
            const unsigned m = wave_min_u32(t0);
            ni_[k] = (int)(m & IMASK);
            const bool win = (t0 == m);
            t0 = win ? t1 : t0; t1 = win ? t2 : t1; t2 = win ? t3 : t2; t3 = win ? ~0u : t3;
        }
        const float* fqp = fq + (size_t)(qbase + q) * 96;
        const float qf0 = fqp[lane];
        const float qf1 = (lane < 32) ? fqp[64 + lane] : 0.0f;
        const float ssq = wave_reduce_sum(qf0*qf0 + qf1*qf1);
        float sim[4];
        #pragma unroll
        for (int k = 0; k < 4; ++k) {
            const float* fdp = fd + (size_t)ni_[k] * 96;
            const float df0 = fdp[lane];
            const float df1 = (lane < 32) ? fdp[64 + lane] : 0.0f;
            const float dotv = wave_reduce_sum(qf0*df0 + qf1*df1);
            const float ssd = wave_reduce_sum(df0*df0 + df1*df1);
            sim[k] = dotv * rsqrtf(fmaxf(ssq, 1e-24f) * fmaxf(ssd, 1e-24f)) * 10.0f;
        }
        const float m = fmaxf(fmaxf(sim[0], sim[1]), fmaxf(sim[2], sim[3]));
        const float e0 = __expf(sim[0]-m), e1 = __expf(sim[1]-m);
        const float e2 = __expf(sim[2]-m), e3 = __expf(sim[3]-m);
        const float ssum = e0+e1+e2+e3;
        const float inv = 1.0f/ssum;
        const float p2 = (e0*e0+e1*e1+e2*e2+e3*e3)*inv*inv;
        wacc += -__logf(p2 + 1e-12f);
    }
    if (lane == 0) atomicAdd(out, wacc * scale);
}

__global__ __launch_bounds__(256)
void brute_fused(const float* __restrict__ ci, const float* __restrict__ fi, int Ni,
                 const float* __restrict__ cj, const float* __restrict__ fj, int Nj,
                 float s0, float s1, int B0, int B1, float* __restrict__ out)
{
    const int bid = (int)blockIdx.x;
    const int bmin = (B0 < B1) ? B0 : B1;
    int dir, blk;
    if (bid < 2 * bmin) { dir = bid & 1; blk = bid >> 1; }
    else { dir = (B0 > B1) ? 0 : 1; blk = bid - bmin; }
    if (dir == 0) brute_dir<8>(ci, fi, Ni, cj, fj, Nj, s0, out, blk);
    else          brute_dir<4>(cj, fj, Nj, ci, fi, Ni, s1, out, blk);
}

// ============================ launch ============================

extern "C" void kernel_launch(void* const* d_in, const int* in_sizes, int n_in,
                              void* d_out, int out_size, void* d_ws, size_t ws_size,
                              hipStream_t stream) {
    const float* feat_i  = (const float*)d_in[0];
    const float* coord_i = (const float*)d_in[1];
    const float* feat_j  = (const float*)d_in[2];
    const float* coord_j = (const float*)d_in[3];
    const int Ni = in_sizes[0] / 96;
    const int Nj = in_sizes[2] / 96;
    float* out = (float*)d_out;

    auto gridfor = [](int n) {
        int g = (int)cbrtf((float)n / 4.5f);
        if (g < 2) g = 2;
        if (g > 24) g = 24;   // LDS: (24^3+1+1024)*4 B = 59.4 KB < 64 KB
        return g;
    };
    const int GA = gridfor(Nj), GB = gridfor(Ni);       // A: db=j, B: db=i
    const int GA3 = GA * GA * GA, GB3 = GB * GB * GB;

    size_t off = 0;
    auto alloc = [&](size_t bytes) { size_t o = off; off = (off + bytes + 15) & ~(size_t)15; return o; };
    const size_t o_soA  = alloc((size_t)Nj * 16);
    const size_t o_soB  = alloc((size_t)Ni * 16);
    const size_t o_siA  = alloc((size_t)Nj * 4);
    const size_t o_siB  = alloc((size_t)Ni * 4);
    const size_t o_stA  = alloc((size_t)(GA3 + 1) * 4);
    const size_t o_stB  = alloc((size_t)(GB3 + 1) * 4);
    const size_t o_part = alloc(64 * 4);

    if (ws_size >= off && Ni >= 16 && Nj >= 16 && Ni <= 32000 && Nj <= 32000) {
        char* W = (char*)d_ws;
        float4* soA = (float4*)(W + o_soA);
        float4* soB = (float4*)(W + o_soB);
        int* siA = (int*)(W + o_siA);
        int* siB = (int*)(W + o_siB);
        int* stA = (int*)(W + o_stA);
        int* stB = (int*)(W + o_stB);
        float* part = (float*)(W + o_part);

        const int G3max = (GA3 > GB3) ? GA3 : GB3;
        const size_t ldsBytes = (size_t)(G3max + 1 + 1024) * 4;

        build_grids<<<2, 1024, ldsBytes, stream>>>(
            coord_j, Nj, GA, stA, soA, siA,
            coord_i, Ni, GB, stB, soB, siB,
            part);

        const int nQ = Ni + Nj;
        const int nblk = (nQ * 16 + 255) / 256;
        knnloss<<<nblk, 256, 0, stream>>>(
            coord_i, feat_i, Ni, coord_j, feat_j, Nj,
            soA, stA, siA, GA, soB, stB, siB, GB,
            0.5f / (float)Ni, 0.5f / (float)Nj, part);
        final_sum<<<1, 64, 0, stream>>>(part, out);
    } else {
        hipMemsetAsync(out, 0, sizeof(float), stream);
        const int waves0 = (Ni + 7) / 8;
        const int B0 = (waves0 + WPB - 1) / WPB;
        const int waves1 = (Nj + 3) / 4;
        const int B1 = (waves1 + WPB - 1) / WPB;
        brute_fused<<<B0 + B1, 256, 0, stream>>>(
            coord_i, feat_i, Ni, coord_j, feat_j, Nj,
            0.5f / (float)Ni, 0.5f / (float)Nj, B0, B1, out);
    }
}

// Round 12
// 89.125 us; speedup vs baseline: 1.0264x; 1.0264x over previous
//
#include <hip/hip_runtime.h>
#include <math.h>

#define KMASK 0xFFFF8000u
#define IMASK 0x7FFFu

__device__ __forceinline__ float wave_reduce_sum(float v) {
    #pragma unroll
    for (int off = 32; off >= 1; off >>= 1) v += __shfl_xor(v, off, 64);
    return v;
}

__device__ __forceinline__ unsigned wave_min_u32(unsigned v) {
    #pragma unroll
    for (int off = 32; off >= 1; off >>= 1) {
        unsigned o = (unsigned)__shfl_xor((int)v, off, 64);
        v = (o < v) ? o : v;
    }
    return v;
}

// reductions over aligned 16-lane group (xor 8,4,2,1 stays in-group)
__device__ __forceinline__ unsigned gmin16(unsigned v) {
    #pragma unroll
    for (int off = 8; off >= 1; off >>= 1) {
        unsigned o = (unsigned)__shfl_xor((int)v, off, 64);
        v = (o < v) ? o : v;
    }
    return v;
}
__device__ __forceinline__ float gsum16(float v) {
    #pragma unroll
    for (int off = 8; off >= 1; off >>= 1) v += __shfl_xor(v, off, 64);
    return v;
}

// sorted ascending insert of packed key into 4-element list
__device__ __forceinline__ void insert4u(unsigned k, unsigned (&b)[4]) {
    const bool c0 = k < b[0], c1 = k < b[1], c2 = k < b[2], c3 = k < b[3];
    b[3] = c2 ? b[2] : (c3 ? k : b[3]);
    b[2] = c1 ? b[1] : (c2 ? k : b[2]);
    b[1] = c0 ? b[0] : (c1 ? k : b[1]);
    b[0] = c0 ? k : b[0];
}

__device__ __forceinline__ int cell_of(float x, int G) {
    int c = (int)(x * (float)G);
    return (c < 0) ? 0 : ((c >= G) ? G - 1 : c);
}

__device__ __forceinline__ float dot2(float2 a, float2 b) {
    return fmaf(a.y, b.y, a.x * b.x);
}

// ================= build: one block per direction, grid in LDS =================

__global__ __launch_bounds__(1024)
void build_grids(const float* __restrict__ cA, int nA, int GA, int* __restrict__ stA,
                 float4* __restrict__ soA, int* __restrict__ siA,
                 const float* __restrict__ cB, int nB, int GB, int* __restrict__ stB,
                 float4* __restrict__ soB, int* __restrict__ siB,
                 float* __restrict__ part)
{
    extern __shared__ int lds[];
    const bool b0 = (blockIdx.x == 0);
    const float* c = b0 ? cA : cB;
    const int    n = b0 ? nA : nB;
    const int    G = b0 ? GA : GB;
    int*        st = b0 ? stA : stB;
    float4*     so = b0 ? soA : soB;
    int*        si = b0 ? siA : siB;
    const int   G3 = G * G * G;
    const int    t = threadIdx.x;
    int* cnt = lds;            // G3+1 entries
    int* scr = lds + G3 + 1;   // 1024 entries

    for (int i = t; i <= G3; i += 1024) cnt[i] = 0;
    if (b0 && t < 64) part[t] = 0.0f;
    __syncthreads();

    for (int p = t; p < n; p += 1024) {
        const int cx = cell_of(c[3*p], G), cy = cell_of(c[3*p+1], G), cz = cell_of(c[3*p+2], G);
        atomicAdd(&cnt[(cz * G + cy) * G + cx + 1], 1);
    }
    __syncthreads();

    const int len = G3 + 1;
    const int chunk = (len + 1023) >> 10;
    const int lo = t * chunk;
    const int hi = (lo + chunk < len) ? (lo + chunk) : len;
    int sum = 0;
    for (int i = lo; i < hi; ++i) sum += cnt[i];
    scr[t] = sum;
    __syncthreads();
    for (int d = 1; d < 1024; d <<= 1) {
        const int v = (t >= d) ? scr[t - d] : 0;
        __syncthreads();
        scr[t] += v;
        __syncthreads();
    }
    int run = (t > 0) ? scr[t - 1] : 0;
    for (int i = lo; i < hi; ++i) {
        run += cnt[i];
        cnt[i] = run;
        st[i] = run;
    }
    __syncthreads();

    for (int p = t; p < n; p += 1024) {
        const float x = c[3*p], y = c[3*p+1], z = c[3*p+2];
        const int cx = cell_of(x, G), cy = cell_of(y, G), cz = cell_of(z, G);
        const int pos = atomicAdd(&cnt[(cz * G + cy) * G + cx], 1);
        so[pos] = make_float4(x, y, z, x*x + y*y + z*z);
        si[pos] = p;
    }
}

// ============= fused grid KNN + loss, queries in grid-sorted order =============
// 16 lanes per query. Query slot t -> original index si_q[t]; coords+|q|^2
// from so_q[t] (coalesced). Adjacent groups probe overlapping cells -> L2 hits.

__global__ __launch_bounds__(256)
void knnloss(const float* __restrict__ fi, int Ni,
             const float* __restrict__ fj, int Nj,
             const float4* __restrict__ soA, const int* __restrict__ stA,
             const int* __restrict__ siA, int GA,
             const float4* __restrict__ soB, const int* __restrict__ stB,
             const int* __restrict__ siB, int GB,
             float sc0, float sc1, float* __restrict__ part)
{
    const int sub = threadIdx.x & 15;
    const int qid = (blockIdx.x * 256 + threadIdx.x) >> 4;
    float acc = 0.0f;

    if (qid < Ni + Nj) {
        const bool d0 = (qid < Ni);
        const int sq = d0 ? qid : qid - Ni;       // slot in the query cloud's sorted array
        // query side: own cloud's sorted arrays (B holds cloud i, A holds cloud j)
        const float4* soq = d0 ? soB : soA;
        const int*    siq = d0 ? siB : siA;
        // db side: the other cloud's grid
        const float4* so = d0 ? soA : soB;
        const int*    st = d0 ? stA : stB;
        const int*    si = d0 ? siA : siB;
        const int      G = d0 ? GA  : GB;
        const int     nd = d0 ? Nj  : Ni;
        const float*  fd = d0 ? fj  : fi;
        const float scale = d0 ? sc0 : sc1;

        const int p = siq[sq];                    // original query index
        const float4 Q = soq[sq];                 // x,y,z,|q|^2 (coalesced)
        const float* fqp = (d0 ? fi : fj) + (size_t)p * 96;

        // hoisted q-feature fragment (independent of KNN chain)
        const float2* q2 = (const float2*)fqp;
        const float2 qa = q2[3*sub], qb = q2[3*sub+1], qc = q2[3*sub+2];

        const float qx = Q.x, qy = Q.y, qz = Q.z;
        const float qq = Q.w;
        const float h = 1.0f / (float)G;
        const int cx = cell_of(qx, G), cy = cell_of(qy, G), cz = cell_of(qz, G);
        const float m2x = -2.0f*qx, m2y = -2.0f*qy, m2z = -2.0f*qz;
        unsigned mk[4];

        // ---------- fast path: s = 1, 3x3 rows prefetched ----------
        {
            const int x0 = max(cx - 1, 0), x1 = min(cx + 1, G - 1);
            int csr[9], cer[9];
            #pragma unroll
            for (int dz = 0; dz < 3; ++dz) {
                #pragma unroll
                for (int dy = 0; dy < 3; ++dy) {
                    const int zz = cz + dz - 1, yy = cy + dy - 1;
                    const bool v = ((unsigned)zz < (unsigned)G) & ((unsigned)yy < (unsigned)G);
                    const int rb = v ? (zz * G + yy) * G : 0;
                    csr[dz*3+dy] = v ? st[rb + x0] : 0;
                    cer[dz*3+dy] = v ? st[rb + x1 + 1] : 0;
                }
            }
            unsigned bk[4] = {~0u, ~0u, ~0u, ~0u};
            #pragma unroll
            for (int r = 0; r < 9; ++r) {
                for (int cc = csr[r] + sub; cc < cer[r]; cc += 16) {
                    const float4 P = so[cc];
                    const float d2 =
                        fmaf(P.z, m2z, fmaf(P.y, m2y, fmaf(P.x, m2x, P.w))) + qq;
                    const unsigned k =
                        (__float_as_uint(fmaxf(d2, 0.0f)) & KMASK) | (unsigned)cc;
                    insert4u(k, bk);
                }
            }
            unsigned t0 = bk[0], t1 = bk[1], t2 = bk[2], t3 = bk[3];
            #pragma unroll
            for (int r = 0; r < 4; ++r) {
                const unsigned m = gmin16(t0);
                mk[r] = m;
                const bool win = (t0 == m);
                t0 = win ? t1 : t0;
                t1 = win ? t2 : t1;
                t2 = win ? t3 : t2;
                t3 = win ? ~0u : t3;
            }
            const int y0 = max(cy - 1, 0), y1 = min(cy + 1, G - 1);
            const int z0 = max(cz - 1, 0), z1 = min(cz + 1, G - 1);
            float margin = 3.0e38f;
            if (x0 > 0)     margin = fminf(margin, qx - (float)x0 * h);
            if (x1 < G - 1) margin = fminf(margin, (float)(x1 + 1) * h - qx);
            if (y0 > 0)     margin = fminf(margin, qy - (float)y0 * h);
            if (y1 < G - 1) margin = fminf(margin, (float)(y1 + 1) * h - qy);
            if (z0 > 0)     margin = fminf(margin, qz - (float)z0 * h);
            if (z1 < G - 1) margin = fminf(margin, (float)(z1 + 1) * h - qz);
            const bool covered = (margin > 1.0e37f);
            const float kd = __uint_as_float(mk[3] & KMASK);
            const bool ok = covered || (kd * 1.01f <= margin * margin);

            // ---------- slow path (rare): expanding box from s = 2 ----------
            if (!ok) {
                for (int s = 2; ; ++s) {
                    const int sx0 = max(cx - s, 0), sx1 = min(cx + s, G - 1);
                    const int sy0 = max(cy - s, 0), sy1 = min(cy + s, G - 1);
                    const int sz0 = max(cz - s, 0), sz1 = min(cz + s, G - 1);
                    unsigned b2[4] = {~0u, ~0u, ~0u, ~0u};
                    for (int z = sz0; z <= sz1; ++z) {
                        for (int y = sy0; y <= sy1; ++y) {
                            const int rb = (z * G + y) * G;
                            const int cs = st[rb + sx0];
                            const int ce = st[rb + sx1 + 1];
                            for (int cc = cs + sub; cc < ce; cc += 16) {
                                const float4 P = so[cc];
                                const float d2 =
                                    fmaf(P.z, m2z, fmaf(P.y, m2y, fmaf(P.x, m2x, P.w))) + qq;
                                const unsigned k =
                                    (__float_as_uint(fmaxf(d2, 0.0f)) & KMASK) | (unsigned)cc;
                                insert4u(k, b2);
                            }
                        }
                    }
                    unsigned u0 = b2[0], u1 = b2[1], u2 = b2[2], u3 = b2[3];
                    #pragma unroll
                    for (int r = 0; r < 4; ++r) {
                        const unsigned m = gmin16(u0);
                        mk[r] = m;
                        const bool win = (u0 == m);
                        u0 = win ? u1 : u0;
                        u1 = win ? u2 : u1;
                        u2 = win ? u3 : u2;
                        u3 = win ? ~0u : u3;
                    }
                    float mg = 3.0e38f;
                    if (sx0 > 0)     mg = fminf(mg, qx - (float)sx0 * h);
                    if (sx1 < G - 1) mg = fminf(mg, (float)(sx1 + 1) * h - qx);
                    if (sy0 > 0)     mg = fminf(mg, qy - (float)sy0 * h);
                    if (sy1 < G - 1) mg = fminf(mg, (float)(sy1 + 1) * h - qy);
                    if (sz0 > 0)     mg = fminf(mg, qz - (float)sz0 * h);
                    if (sz1 < G - 1) mg = fminf(mg, (float)(sz1 + 1) * h - qz);
                    const bool cov = (mg > 1.0e37f);
                    const float k2 = __uint_as_float(mk[3] & KMASK);
                    if (cov || (k2 * 1.01f <= mg * mg)) break;
                }
            }
        }

        // ---------- feature phase: all loads issued, then reductions ----------
        const int nm1 = nd - 1;
        const int i0 = si[min((int)(mk[0] & IMASK), nm1)];
        const int i1 = si[min((int)(mk[1] & IMASK), nm1)];
        const int i2 = si[min((int)(mk[2] & IMASK), nm1)];
        const int i3 = si[min((int)(mk[3] & IMASK), nm1)];

        const float2* f0 = (const float2*)(fd + (size_t)i0 * 96);
        const float2* f1 = (const float2*)(fd + (size_t)i1 * 96);
        const float2* f2 = (const float2*)(fd + (size_t)i2 * 96);
        const float2* f3 = (const float2*)(fd + (size_t)i3 * 96);
        const float2 a0 = f0[3*sub], b0 = f0[3*sub+1], c0 = f0[3*sub+2];
        const float2 a1 = f1[3*sub], b1 = f1[3*sub+1], c1 = f1[3*sub+2];
        const float2 a2 = f2[3*sub], b2 = f2[3*sub+1], c2 = f2[3*sub+2];
        const float2 a3 = f3[3*sub], b3 = f3[3*sub+1], c3 = f3[3*sub+2];

        const float ssq = gsum16(dot2(qa,qa) + dot2(qb,qb) + dot2(qc,qc));

        float sim[4];
        {
            const float dv = gsum16(dot2(qa,a0) + dot2(qb,b0) + dot2(qc,c0));
            const float sd = gsum16(dot2(a0,a0) + dot2(b0,b0) + dot2(c0,c0));
            sim[0] = dv * rsqrtf(fmaxf(ssq, 1e-24f) * fmaxf(sd, 1e-24f)) * 10.0f;
        }
        {
            const float dv = gsum16(dot2(qa,a1) + dot2(qb,b1) + dot2(qc,c1));
            const float sd = gsum16(dot2(a1,a1) + dot2(b1,b1) + dot2(c1,c1));
            sim[1] = dv * rsqrtf(fmaxf(ssq, 1e-24f) * fmaxf(sd, 1e-24f)) * 10.0f;
        }
        {
            const float dv = gsum16(dot2(qa,a2) + dot2(qb,b2) + dot2(qc,c2));
            const float sd = gsum16(dot2(a2,a2) + dot2(b2,b2) + dot2(c2,c2));
            sim[2] = dv * rsqrtf(fmaxf(ssq, 1e-24f) * fmaxf(sd, 1e-24f)) * 10.0f;
        }
        {
            const float dv = gsum16(dot2(qa,a3) + dot2(qb,b3) + dot2(qc,c3));
            const float sd = gsum16(dot2(a3,a3) + dot2(b3,b3) + dot2(c3,c3));
            sim[3] = dv * rsqrtf(fmaxf(ssq, 1e-24f) * fmaxf(sd, 1e-24f)) * 10.0f;
        }

        const float m = fmaxf(fmaxf(sim[0], sim[1]), fmaxf(sim[2], sim[3]));
        const float e0 = __expf(sim[0] - m), e1 = __expf(sim[1] - m);
        const float e2 = __expf(sim[2] - m), e3 = __expf(sim[3] - m);
        const float ssum = e0 + e1 + e2 + e3;
        const float inv = 1.0f / ssum;
        const float p2 = (e0*e0 + e1*e1 + e2*e2 + e3*e3) * inv * inv;
        if (sub == 0) acc = -__logf(p2 + 1e-12f) * scale;
    }

    acc = wave_reduce_sum(acc);
    if ((threadIdx.x & 63) == 0) atomicAdd(&part[blockIdx.x & 63], acc);
}

__global__ __launch_bounds__(64)
void final_sum(const float* __restrict__ partial, float* __restrict__ out) {
    float v = partial[threadIdx.x];
    v = wave_reduce_sum(v);
    if (threadIdx.x == 0) out[0] = v;
}

// ============================ brute fallback ============================

#define WPB 4
template<int QPW>
__device__ __forceinline__ void brute_dir(
    const float* __restrict__ cq, const float* __restrict__ fq, int Nq,
    const float* __restrict__ cd, const float* __restrict__ fd, int Nd,
    float scale, float* __restrict__ out, int blk)
{
    const int lane = threadIdx.x & 63;
    const int widx = threadIdx.x >> 6;
    int qbase = (blk * WPB + widx) * QPW;
    if (qbase >= Nq) return;
    qbase = __builtin_amdgcn_readfirstlane(qbase);

    float qx[QPW], qy[QPW], qz[QPW];
    #pragma unroll
    for (int q = 0; q < QPW; ++q) {
        const int qi = (qbase + q < Nq) ? (qbase + q) : (Nq - 1);
        qx[q] = cq[qi*3]; qy[q] = cq[qi*3+1]; qz[q] = cq[qi*3+2];
    }
    unsigned bk[QPW][4];
    #pragma unroll
    for (int q = 0; q < QPW; ++q) {
        #pragma unroll
        for (int k = 0; k < 4; ++k) bk[q][k] = ~0u;
    }
    for (int base = 0; base < Nd; base += 64) {
        const int p = base + lane;
        const int cp = (p < Nd) ? p : (Nd - 1);
        const float px = cd[cp*3], py = cd[cp*3+1], pz = cd[cp*3+2];
        #pragma unroll
        for (int q = 0; q < QPW; ++q) {
            const float dx = px - qx[q], dy = py - qy[q], dz = pz - qz[q];
            const float d2 = dx*dx + dy*dy + dz*dz;
            unsigned k = (__float_as_uint(d2) & KMASK) | (unsigned)p;
            if (p >= Nd) k = ~0u;
            insert4u(k, bk[q]);
        }
    }
    float wacc = 0.0f;
    #pragma unroll
    for (int q = 0; q < QPW; ++q) {
        if (qbase + q >= Nq) break;
        unsigned t0 = bk[q][0], t1 = bk[q][1], t2 = bk[q][2], t3 = bk[q][3];
        int ni_[4];
        #pragma unroll
        for (int k = 0; k < 4; ++k) {
            const unsigned m = wave_min_u32(t0);
            ni_[k] = (int)(m & IMASK);
            const bool win = (t0 == m);
            t0 = win ? t1 : t0; t1 = win ? t2 : t1; t2 = win ? t3 : t2; t3 = win ? ~0u : t3;
        }
        const float* fqp = fq + (size_t)(qbase + q) * 96;
        const float qf0 = fqp[lane];
        const float qf1 = (lane < 32) ? fqp[64 + lane] : 0.0f;
        const float ssq = wave_reduce_sum(qf0*qf0 + qf1*qf1);
        float sim[4];
        #pragma unroll
        for (int k = 0; k < 4; ++k) {
            const float* fdp = fd + (size_t)ni_[k] * 96;
            const float df0 = fdp[lane];
            const float df1 = (lane < 32) ? fdp[64 + lane] : 0.0f;
            const float dotv = wave_reduce_sum(qf0*df0 + qf1*df1);
            const float ssd = wave_reduce_sum(df0*df0 + df1*df1);
            sim[k] = dotv * rsqrtf(fmaxf(ssq, 1e-24f) * fmaxf(ssd, 1e-24f)) * 10.0f;
        }
        const float m = fmaxf(fmaxf(sim[0], sim[1]), fmaxf(sim[2], sim[3]));
        const float e0 = __expf(sim[0]-m), e1 = __expf(sim[1]-m);
        const float e2 = __expf(sim[2]-m), e3 = __expf(sim[3]-m);
        const float ssum = e0+e1+e2+e3;
        const float inv = 1.0f/ssum;
        const float p2 = (e0*e0+e1*e1+e2*e2+e3*e3)*inv*inv;
        wacc += -__logf(p2 + 1e-12f);
    }
    if (lane == 0) atomicAdd(out, wacc * scale);
}

__global__ __launch_bounds__(256)
void brute_fused(const float* __restrict__ ci, const float* __restrict__ fi, int Ni,
                 const float* __restrict__ cj, const float* __restrict__ fj, int Nj,
                 float s0, float s1, int B0, int B1, float* __restrict__ out)
{
    const int bid = (int)blockIdx.x;
    const int bmin = (B0 < B1) ? B0 : B1;
    int dir, blk;
    if (bid < 2 * bmin) { dir = bid & 1; blk = bid >> 1; }
    else { dir = (B0 > B1) ? 0 : 1; blk = bid - bmin; }
    if (dir == 0) brute_dir<8>(ci, fi, Ni, cj, fj, Nj, s0, out, blk);
    else          brute_dir<4>(cj, fj, Nj, ci, fi, Ni, s1, out, blk);
}

// ============================ launch ============================

extern "C" void kernel_launch(void* const* d_in, const int* in_sizes, int n_in,
                              void* d_out, int out_size, void* d_ws, size_t ws_size,
                              hipStream_t stream) {
    const float* feat_i  = (const float*)d_in[0];
    const float* coord_i = (const float*)d_in[1];
    const float* feat_j  = (const float*)d_in[2];
    const float* coord_j = (const float*)d_in[3];
    const int Ni = in_sizes[0] / 96;
    const int Nj = in_sizes[2] / 96;
    float* out = (float*)d_out;

    auto gridfor = [](int n) {
        int g = (int)cbrtf((float)n / 4.5f);
        if (g < 2) g = 2;
        if (g > 24) g = 24;   // LDS: (24^3+1+1024)*4 B = 59.4 KB < 64 KB
        return g;
    };
    const int GA = gridfor(Nj), GB = gridfor(Ni);       // A: cloud j, B: cloud i
    const int GA3 = GA * GA * GA, GB3 = GB * GB * GB;

    size_t off = 0;
    auto alloc = [&](size_t bytes) { size_t o = off; off = (off + bytes + 15) & ~(size_t)15; return o; };
    const size_t o_soA  = alloc((size_t)Nj * 16);
    const size_t o_soB  = alloc((size_t)Ni * 16);
    const size_t o_siA  = alloc((size_t)Nj * 4);
    const size_t o_siB  = alloc((size_t)Ni * 4);
    const size_t o_stA  = alloc((size_t)(GA3 + 1) * 4);
    const size_t o_stB  = alloc((size_t)(GB3 + 1) * 4);
    const size_t o_part = alloc(64 * 4);

    if (ws_size >= off && Ni >= 16 && Nj >= 16 && Ni <= 32000 && Nj <= 32000) {
        char* W = (char*)d_ws;
        float4* soA = (float4*)(W + o_soA);
        float4* soB = (float4*)(W + o_soB);
        int* siA = (int*)(W + o_siA);
        int* siB = (int*)(W + o_siB);
        int* stA = (int*)(W + o_stA);
        int* stB = (int*)(W + o_stB);
        float* part = (float*)(W + o_part);

        const int G3max = (GA3 > GB3) ? GA3 : GB3;
        const size_t ldsBytes = (size_t)(G3max + 1 + 1024) * 4;

        build_grids<<<2, 1024, ldsBytes, stream>>>(
            coord_j, Nj, GA, stA, soA, siA,
            coord_i, Ni, GB, stB, soB, siB,
            part);

        const int nQ = Ni + Nj;
        const int nblk = (nQ * 16 + 255) / 256;
        knnloss<<<nblk, 256, 0, stream>>>(
            feat_i, Ni, feat_j, Nj,
            soA, stA, siA, GA, soB, stB, siB, GB,
            0.5f / (float)Ni, 0.5f / (float)Nj, part);
        final_sum<<<1, 64, 0, stream>>>(part, out);
    } else {
        hipMemsetAsync(out, 0, sizeof(float), stream);
        const int waves0 = (Ni + 7) / 8;
        const int B0 = (waves0 + WPB - 1) / WPB;
        const int waves1 = (Nj + 3) / 4;
        const int B1 = (waves1 + WPB - 1) / WPB;
        brute_fused<<<B0 + B1, 256, 0, stream>>>(
            coord_i, feat_i, Ni, coord_j, feat_j, Nj,
            0.5f / (float)Ni, 0.5f / (float)Nj, B0, B1, out);
    }
}

// Round 13
// 60.969 us; speedup vs baseline: 1.5004x; 1.4618x over previous
//
#include <hip/hip_runtime.h>
#include <math.h>

#define KMASK 0xFFFF8000u
#define IMASK 0x7FFFu

__device__ __forceinline__ float wave_reduce_sum(float v) {
    #pragma unroll
    for (int off = 32; off >= 1; off >>= 1) v += __shfl_xor(v, off, 64);
    return v;
}

__device__ __forceinline__ unsigned wave_min_u32(unsigned v) {
    #pragma unroll
    for (int off = 32; off >= 1; off >>= 1) {
        unsigned o = (unsigned)__shfl_xor((int)v, off, 64);
        v = (o < v) ? o : v;
    }
    return v;
}

// reductions over aligned 8-lane group (xor 4,2,1 stays in-group)
__device__ __forceinline__ unsigned gmin8(unsigned v) {
    #pragma unroll
    for (int off = 4; off >= 1; off >>= 1) {
        unsigned o = (unsigned)__shfl_xor((int)v, off, 64);
        v = (o < v) ? o : v;
    }
    return v;
}
__device__ __forceinline__ float gsum8(float v) {
    #pragma unroll
    for (int off = 4; off >= 1; off >>= 1) v += __shfl_xor(v, off, 64);
    return v;
}

// sorted ascending insert of (key,value) into 4-element lists
__device__ __forceinline__ void insert4kv(unsigned k, unsigned v,
                                          unsigned (&bk)[4], unsigned (&bv)[4]) {
    const bool c0 = k < bk[0], c1 = k < bk[1], c2 = k < bk[2], c3 = k < bk[3];
    bk[3] = c2 ? bk[2] : (c3 ? k : bk[3]);
    bv[3] = c2 ? bv[2] : (c3 ? v : bv[3]);
    bk[2] = c1 ? bk[1] : (c2 ? k : bk[2]);
    bv[2] = c1 ? bv[1] : (c2 ? v : bv[2]);
    bk[1] = c0 ? bk[0] : (c1 ? k : bk[1]);
    bv[1] = c0 ? bv[0] : (c1 ? v : bv[1]);
    bk[0] = c0 ? k : bk[0];
    bv[0] = c0 ? v : bv[0];
}

__device__ __forceinline__ int cell_of(float x, int G) {
    int c = (int)(x * (float)G);
    return (c < 0) ? 0 : ((c >= G) ? G - 1 : c);
}

__device__ __forceinline__ float dot4(float4 a, float4 b) {
    return fmaf(a.w, b.w, fmaf(a.z, b.z, fmaf(a.y, b.y, a.x * b.x)));
}

// ============================ grid build (parallel) ============================

__global__ __launch_bounds__(256)
void grid_zero(int* __restrict__ stA, int nA, int* __restrict__ stB, int nB,
               float* __restrict__ part)
{
    const int t = blockIdx.x * 256 + threadIdx.x;
    if (t < nA) stA[t] = 0;
    if (t < nB) stB[t] = 0;
    if (t < 64) part[t] = 0.0f;
}

__global__ __launch_bounds__(256)
void grid_count(const float* __restrict__ cA, int nA, int GA, int* __restrict__ stA,
                const float* __restrict__ cB, int nB, int GB, int* __restrict__ stB)
{
    const int t = blockIdx.x * 256 + threadIdx.x;
    const float* c; int* s; int G; int p;
    if (t < nA)           { c = cA; s = stA; G = GA; p = t; }
    else if (t < nA + nB) { c = cB; s = stB; G = GB; p = t - nA; }
    else return;
    const int cx = cell_of(c[3*p], G), cy = cell_of(c[3*p+1], G), cz = cell_of(c[3*p+2], G);
    atomicAdd(&s[(cz * G + cy) * G + cx + 1], 1);
}

// in-place inclusive scan of s[0..n]; also writes cu[i] = s[i] (cell cursors)
__global__ __launch_bounds__(256)
void grid_scan(int* __restrict__ sA, int nA, int* __restrict__ cuA,
               int* __restrict__ sB, int nB, int* __restrict__ cuB)
{
    int* s  = blockIdx.x ? sB  : sA;
    int* cu = blockIdx.x ? cuB : cuA;
    const int n = blockIdx.x ? nB : nA;
    __shared__ int part[256];
    const int t = threadIdx.x;
    const int len = n + 1;
    const int chunk = (len + 255) >> 8;
    const int lo = t * chunk;
    const int hi = (lo + chunk < len) ? (lo + chunk) : len;
    int sum = 0;
    for (int i = lo; i < hi; ++i) sum += s[i];
    part[t] = sum;
    __syncthreads();
    for (int d = 1; d < 256; d <<= 1) {
        const int v = (t >= d) ? part[t - d] : 0;
        __syncthreads();
        part[t] += v;
        __syncthreads();
    }
    int run = (t > 0) ? part[t - 1] : 0;
    for (int i = lo; i < hi; ++i) {
        run += s[i];
        s[i] = run;
        if (i < n) cu[i] = run;
    }
}

// scatter: so[pos] = {x, y, z, bits(original_index)}
__global__ __launch_bounds__(256)
void grid_scatter(const float* __restrict__ cA, int nA, int GA, int* __restrict__ cuA,
                  float4* __restrict__ soA,
                  const float* __restrict__ cB, int nB, int GB, int* __restrict__ cuB,
                  float4* __restrict__ soB)
{
    const int t = blockIdx.x * 256 + threadIdx.x;
    const float* c; int* cu; float4* so; int G; int p;
    if (t < nA)           { c = cA; cu = cuA; so = soA; G = GA; p = t; }
    else if (t < nA + nB) { c = cB; cu = cuB; so = soB; G = GB; p = t - nA; }
    else return;
    const float x = c[3*p], y = c[3*p+1], z = c[3*p+2];
    const int cx = cell_of(x, G), cy = cell_of(y, G), cz = cell_of(z, G);
    const int pos = atomicAdd(&cu[(cz * G + cy) * G + cx], 1);
    so[pos] = make_float4(x, y, z, __uint_as_float((unsigned)p));
}

// ============= fused grid KNN + loss, 8 lanes/query, sorted order =============
// Chain: soq -> st(18, prefetched) -> so-sweep -> features. Original indices
// ride in so.w through the (key,value) top-4 lists: no si level.

__global__ __launch_bounds__(256)
void knnloss(const float* __restrict__ fi, int Ni,
             const float* __restrict__ fj, int Nj,
             const float4* __restrict__ soA, const int* __restrict__ stA, int GA,
             const float4* __restrict__ soB, const int* __restrict__ stB, int GB,
             float sc0, float sc1, float* __restrict__ part)
{
    const int sub = threadIdx.x & 7;
    const int qid = (blockIdx.x * 256 + threadIdx.x) >> 3;
    float acc = 0.0f;

    if (qid < Ni + Nj) {
        const bool d0 = (qid < Ni);
        const int sq = d0 ? qid : qid - Ni;       // slot in own cloud's sorted array
        const float4* soq = d0 ? soB : soA;       // B = cloud i sorted, A = cloud j sorted
        const float4* so = d0 ? soA : soB;        // db = other cloud
        const int*    st = d0 ? stA : stB;
        const int      G = d0 ? GA  : GB;
        const int     nd = d0 ? Nj  : Ni;
        const float*  fd = d0 ? fj  : fi;
        const float scale = d0 ? sc0 : sc1;

        const float4 Q = soq[sq];                 // x,y,z,bits(orig idx)
        const unsigned p = __float_as_uint(Q.w);
        const float* fqp = (d0 ? fi : fj) + (size_t)p * 96;

        // hoisted q-feature fragment (depends only on Q)
        const float4* q4 = (const float4*)fqp;
        const float4 qa = q4[3*sub], qb = q4[3*sub+1], qc = q4[3*sub+2];

        const float qx = Q.x, qy = Q.y, qz = Q.z;
        const float h = 1.0f / (float)G;
        const int cx = cell_of(qx, G), cy = cell_of(qy, G), cz = cell_of(qz, G);
        unsigned nk[4], nv[4];

        // ---------- fast path: s = 1, 3x3 rows prefetched ----------
        {
            const int x0 = max(cx - 1, 0), x1 = min(cx + 1, G - 1);
            int csr[9], cer[9];
            #pragma unroll
            for (int dz = 0; dz < 3; ++dz) {
                #pragma unroll
                for (int dy = 0; dy < 3; ++dy) {
                    const int zz = cz + dz - 1, yy = cy + dy - 1;
                    const bool v = ((unsigned)zz < (unsigned)G) & ((unsigned)yy < (unsigned)G);
                    const int rb = v ? (zz * G + yy) * G : 0;
                    csr[dz*3+dy] = v ? st[rb + x0] : 0;
                    cer[dz*3+dy] = v ? st[rb + x1 + 1] : 0;
                }
            }
            unsigned bk[4] = {~0u, ~0u, ~0u, ~0u};
            unsigned bv[4] = {~0u, ~0u, ~0u, ~0u};
            #pragma unroll
            for (int r = 0; r < 9; ++r) {
                for (int cc = csr[r] + sub; cc < cer[r]; cc += 8) {
                    const float4 P = so[cc];
                    const float dx = P.x - qx, dy = P.y - qy, dz = P.z - qz;
                    const float d2 = fmaf(dx, dx, fmaf(dy, dy, dz * dz));
                    const unsigned k = (__float_as_uint(d2) & KMASK) | (unsigned)cc;
                    insert4kv(k, __float_as_uint(P.w), bk, bv);
                }
            }
            unsigned k0 = bk[0], k1 = bk[1], k2 = bk[2], k3 = bk[3];
            unsigned v0 = bv[0], v1 = bv[1], v2 = bv[2], v3 = bv[3];
            #pragma unroll
            for (int r = 0; r < 4; ++r) {
                const unsigned m = gmin8(k0);
                const bool win = (k0 == m);
                nv[r] = gmin8(win ? v0 : ~0u);
                nk[r] = m;
                k0 = win ? k1 : k0; v0 = win ? v1 : v0;
                k1 = win ? k2 : k1; v1 = win ? v2 : v1;
                k2 = win ? k3 : k2; v2 = win ? v3 : v2;
                k3 = win ? ~0u : k3;
            }
            const int y0 = max(cy - 1, 0), y1 = min(cy + 1, G - 1);
            const int z0 = max(cz - 1, 0), z1 = min(cz + 1, G - 1);
            float margin = 3.0e38f;
            if (x0 > 0)     margin = fminf(margin, qx - (float)x0 * h);
            if (x1 < G - 1) margin = fminf(margin, (float)(x1 + 1) * h - qx);
            if (y0 > 0)     margin = fminf(margin, qy - (float)y0 * h);
            if (y1 < G - 1) margin = fminf(margin, (float)(y1 + 1) * h - qy);
            if (z0 > 0)     margin = fminf(margin, qz - (float)z0 * h);
            if (z1 < G - 1) margin = fminf(margin, (float)(z1 + 1) * h - qz);
            const bool covered = (margin > 1.0e37f);
            const float kd = __uint_as_float(nk[3] & KMASK);   // NaN-bits if <4 found
            const bool ok = covered || (kd * 1.01f <= margin * margin);

            // ---------- slow path (rare): expanding box from s = 2 ----------
            if (!ok) {
                for (int s = 2; ; ++s) {
                    const int sx0 = max(cx - s, 0), sx1 = min(cx + s, G - 1);
                    const int sy0 = max(cy - s, 0), sy1 = min(cy + s, G - 1);
                    const int sz0 = max(cz - s, 0), sz1 = min(cz + s, G - 1);
                    unsigned b2k[4] = {~0u, ~0u, ~0u, ~0u};
                    unsigned b2v[4] = {~0u, ~0u, ~0u, ~0u};
                    for (int z = sz0; z <= sz1; ++z) {
                        for (int y = sy0; y <= sy1; ++y) {
                            const int rb = (z * G + y) * G;
                            const int cs = st[rb + sx0];
                            const int ce = st[rb + sx1 + 1];
                            for (int cc = cs + sub; cc < ce; cc += 8) {
                                const float4 P = so[cc];
                                const float dx = P.x - qx, dy = P.y - qy, dz = P.z - qz;
                                const float d2 = fmaf(dx, dx, fmaf(dy, dy, dz * dz));
                                const unsigned k =
                                    (__float_as_uint(d2) & KMASK) | (unsigned)cc;
                                insert4kv(k, __float_as_uint(P.w), b2k, b2v);
                            }
                        }
                    }
                    unsigned u0 = b2k[0], u1 = b2k[1], u2 = b2k[2], u3 = b2k[3];
                    unsigned w0 = b2v[0], w1 = b2v[1], w2 = b2v[2], w3 = b2v[3];
                    #pragma unroll
                    for (int r = 0; r < 4; ++r) {
                        const unsigned m = gmin8(u0);
                        const bool win = (u0 == m);
                        nv[r] = gmin8(win ? w0 : ~0u);
                        nk[r] = m;
                        u0 = win ? u1 : u0; w0 = win ? w1 : w0;
                        u1 = win ? u2 : u1; w1 = win ? w2 : w1;
                        u2 = win ? u3 : u2; w2 = win ? w3 : w2;
                        u3 = win ? ~0u : u3;
                    }
                    float mg = 3.0e38f;
                    if (sx0 > 0)     mg = fminf(mg, qx - (float)sx0 * h);
                    if (sx1 < G - 1) mg = fminf(mg, (float)(sx1 + 1) * h - qx);
                    if (sy0 > 0)     mg = fminf(mg, qy - (float)sy0 * h);
                    if (sy1 < G - 1) mg = fminf(mg, (float)(sy1 + 1) * h - qy);
                    if (sz0 > 0)     mg = fminf(mg, qz - (float)sz0 * h);
                    if (sz1 < G - 1) mg = fminf(mg, (float)(sz1 + 1) * h - qz);
                    const bool cov = (mg > 1.0e37f);
                    const float k2d = __uint_as_float(nk[3] & KMASK);
                    if (cov || (k2d * 1.01f <= mg * mg)) break;
                }
            }
        }

        // ---------- feature phase: all loads issued, then reductions ----------
        const unsigned nm1 = (unsigned)(nd - 1);
        const unsigned i0 = nv[0] < nm1 ? nv[0] : nm1;
        const unsigned i1 = nv[1] < nm1 ? nv[1] : nm1;
        const unsigned i2 = nv[2] < nm1 ? nv[2] : nm1;
        const unsigned i3 = nv[3] < nm1 ? nv[3] : nm1;

        const float4* f0 = (const float4*)(fd + (size_t)i0 * 96);
        const float4* f1 = (const float4*)(fd + (size_t)i1 * 96);
        const float4* f2 = (const float4*)(fd + (size_t)i2 * 96);
        const float4* f3 = (const float4*)(fd + (size_t)i3 * 96);
        const float4 a0 = f0[3*sub], b0 = f0[3*sub+1], c0 = f0[3*sub+2];
        const float4 a1 = f1[3*sub], b1 = f1[3*sub+1], c1 = f1[3*sub+2];
        const float4 a2 = f2[3*sub], b2 = f2[3*sub+1], c2 = f2[3*sub+2];
        const float4 a3 = f3[3*sub], b3 = f3[3*sub+1], c3 = f3[3*sub+2];

        const float ssq = gsum8(dot4(qa,qa) + dot4(qb,qb) + dot4(qc,qc));

        float sim[4];
        {
            const float dv = gsum8(dot4(qa,a0) + dot4(qb,b0) + dot4(qc,c0));
            const float sd = gsum8(dot4(a0,a0) + dot4(b0,b0) + dot4(c0,c0));
            sim[0] = dv * rsqrtf(fmaxf(ssq, 1e-24f) * fmaxf(sd, 1e-24f)) * 10.0f;
        }
        {
            const float dv = gsum8(dot4(qa,a1) + dot4(qb,b1) + dot4(qc,c1));
            const float sd = gsum8(dot4(a1,a1) + dot4(b1,b1) + dot4(c1,c1));
            sim[1] = dv * rsqrtf(fmaxf(ssq, 1e-24f) * fmaxf(sd, 1e-24f)) * 10.0f;
        }
        {
            const float dv = gsum8(dot4(qa,a2) + dot4(qb,b2) + dot4(qc,c2));
            const float sd = gsum8(dot4(a2,a2) + dot4(b2,b2) + dot4(c2,c2));
            sim[2] = dv * rsqrtf(fmaxf(ssq, 1e-24f) * fmaxf(sd, 1e-24f)) * 10.0f;
        }
        {
            const float dv = gsum8(dot4(qa,a3) + dot4(qb,b3) + dot4(qc,c3));
            const float sd = gsum8(dot4(a3,a3) + dot4(b3,b3) + dot4(c3,c3));
            sim[3] = dv * rsqrtf(fmaxf(ssq, 1e-24f) * fmaxf(sd, 1e-24f)) * 10.0f;
        }

        const float m = fmaxf(fmaxf(sim[0], sim[1]), fmaxf(sim[2], sim[3]));
        const float e0 = __expf(sim[0] - m), e1 = __expf(sim[1] - m);
        const float e2 = __expf(sim[2] - m), e3 = __expf(sim[3] - m);
        const float ssum = e0 + e1 + e2 + e3;
        const float inv = 1.0f / ssum;
        const float p2 = (e0*e0 + e1*e1 + e2*e2 + e3*e3) * inv * inv;
        if (sub == 0) acc = -__logf(p2 + 1e-12f) * scale;
    }

    acc = wave_reduce_sum(acc);
    if ((threadIdx.x & 63) == 0) atomicAdd(&part[blockIdx.x & 63], acc);
}

__global__ __launch_bounds__(64)
void final_sum(const float* __restrict__ partial, float* __restrict__ out) {
    float v = partial[threadIdx.x];
    v = wave_reduce_sum(v);
    if (threadIdx.x == 0) out[0] = v;
}

// ============================ brute fallback ============================

#define WPB 4
__device__ __forceinline__ void insert4u(unsigned k, unsigned (&b)[4]) {
    const bool c0 = k < b[0], c1 = k < b[1], c2 = k < b[2], c3 = k < b[3];
    b[3] = c2 ? b[2] : (c3 ? k : b[3]);
    b[2] = c1 ? b[1] : (c2 ? k : b[2]);
    b[1] = c0 ? b[0] : (c1 ? k : b[1]);
    b[0] = c0 ? k : b[0];
}

template<int QPW>
__device__ __forceinline__ void brute_dir(
    const float* __restrict__ cq, const float* __restrict__ fq, int Nq,
    const float* __restrict__ cd, const float* __restrict__ fd, int Nd,
    float scale, float* __restrict__ out, int blk)
{
    const int lane = threadIdx.x & 63;
    const int widx = threadIdx.x >> 6;
    int qbase = (blk * WPB + widx) * QPW;
    if (qbase >= Nq) return;
    qbase = __builtin_amdgcn_readfirstlane(qbase);

    float qx[QPW], qy[QPW], qz[QPW];
    #pragma unroll
    for (int q = 0; q < QPW; ++q) {
        const int qi = (qbase + q < Nq) ? (qbase + q) : (Nq - 1);
        qx[q] = cq[qi*3]; qy[q] = cq[qi*3+1]; qz[q] = cq[qi*3+2];
    }
    unsigned bk[QPW][4];
    #pragma unroll
    for (int q = 0; q < QPW; ++q) {
        #pragma unroll
        for (int k = 0; k < 4; ++k) bk[q][k] = ~0u;
    }
    for (int base = 0; base < Nd; base += 64) {
        const int p = base + lane;
        const int cp = (p < Nd) ? p : (Nd - 1);
        const float px = cd[cp*3], py = cd[cp*3+1], pz = cd[cp*3+2];
        #pragma unroll
        for (int q = 0; q < QPW; ++q) {
            const float dx = px - qx[q], dy = py - qy[q], dz = pz - qz[q];
            const float d2 = dx*dx + dy*dy + dz*dz;
            unsigned k = (__float_as_uint(d2) & KMASK) | (unsigned)p;
            if (p >= Nd) k = ~0u;
            insert4u(k, bk[q]);
        }
    }
    float wacc = 0.0f;
    #pragma unroll
    for (int q = 0; q < QPW; ++q) {
        if (qbase + q >= Nq) break;
        unsigned t0 = bk[q][0], t1 = bk[q][1], t2 = bk[q][2], t3 = bk[q][3];
        int ni_[4];
        #pragma unroll
        for (int k = 0; k < 4; ++k) {
            const unsigned m = wave_min_u32(t0);
            ni_[k] = (int)(m & IMASK);
            const bool win = (t0 == m);
            t0 = win ? t1 : t0; t1 = win ? t2 : t1; t2 = win ? t3 : t2; t3 = win ? ~0u : t3;
        }
        const float* fqp = fq + (size_t)(qbase + q) * 96;
        const float qf0 = fqp[lane];
        const float qf1 = (lane < 32) ? fqp[64 + lane] : 0.0f;
        const float ssq = wave_reduce_sum(qf0*qf0 + qf1*qf1);
        float sim[4];
        #pragma unroll
        for (int k = 0; k < 4; ++k) {
            const float* fdp = fd + (size_t)ni_[k] * 96;
            const float df0 = fdp[lane];
            const float df1 = (lane < 32) ? fdp[64 + lane] : 0.0f;
            const float dotv = wave_reduce_sum(qf0*df0 + qf1*df1);
            const float ssd = wave_reduce_sum(df0*df0 + df1*df1);
            sim[k] = dotv * rsqrtf(fmaxf(ssq, 1e-24f) * fmaxf(ssd, 1e-24f)) * 10.0f;
        }
        const float m = fmaxf(fmaxf(sim[0], sim[1]), fmaxf(sim[2], sim[3]));
        const float e0 = __expf(sim[0]-m), e1 = __expf(sim[1]-m);
        const float e2 = __expf(sim[2]-m), e3 = __expf(sim[3]-m);
        const float ssum = e0+e1+e2+e3;
        const float inv = 1.0f/ssum;
        const float p2 = (e0*e0+e1*e1+e2*e2+e3*e3)*inv*inv;
        wacc += -__logf(p2 + 1e-12f);
    }
    if (lane == 0) atomicAdd(out, wacc * scale);
}

__global__ __launch_bounds__(256)
void brute_fused(const float* __restrict__ ci, const float* __restrict__ fi, int Ni,
                 const float* __restrict__ cj, const float* __restrict__ fj, int Nj,
                 float s0, float s1, int B0, int B1, float* __restrict__ out)
{
    const int bid = (int)blockIdx.x;
    const int bmin = (B0 < B1) ? B0 : B1;
    int dir, blk;
    if (bid < 2 * bmin) { dir = bid & 1; blk = bid >> 1; }
    else { dir = (B0 > B1) ? 0 : 1; blk = bid - bmin; }
    if (dir == 0) brute_dir<8>(ci, fi, Ni, cj, fj, Nj, s0, out, blk);
    else          brute_dir<4>(cj, fj, Nj, ci, fi, Ni, s1, out, blk);
}

// ============================ launch ============================

extern "C" void kernel_launch(void* const* d_in, const int* in_sizes, int n_in,
                              void* d_out, int out_size, void* d_ws, size_t ws_size,
                              hipStream_t stream) {
    const float* feat_i  = (const float*)d_in[0];
    const float* coord_i = (const float*)d_in[1];
    const float* feat_j  = (const float*)d_in[2];
    const float* coord_j = (const float*)d_in[3];
    const int Ni = in_sizes[0] / 96;
    const int Nj = in_sizes[2] / 96;
    float* out = (float*)d_out;

    auto gridfor = [](int n) {
        int g = (int)cbrtf((float)n / 4.5f);
        if (g < 2) g = 2;
        if (g > 28) g = 28;
        return g;
    };
    const int GA = gridfor(Nj), GB = gridfor(Ni);       // A: cloud j, B: cloud i
    const int GA3 = GA * GA * GA, GB3 = GB * GB * GB;

    size_t off = 0;
    auto alloc = [&](size_t bytes) { size_t o = off; off = (off + bytes + 15) & ~(size_t)15; return o; };
    const size_t o_soA  = alloc((size_t)Nj * 16);
    const size_t o_soB  = alloc((size_t)Ni * 16);
    const size_t o_stA  = alloc((size_t)(GA3 + 1) * 4);
    const size_t o_stB  = alloc((size_t)(GB3 + 1) * 4);
    const size_t o_cuA  = alloc((size_t)GA3 * 4);
    const size_t o_cuB  = alloc((size_t)GB3 * 4);
    const size_t o_part = alloc(64 * 4);

    if (ws_size >= off && Ni >= 16 && Nj >= 16 && Ni <= 32000 && Nj <= 32000) {
        char* W = (char*)d_ws;
        float4* soA = (float4*)(W + o_soA);
        float4* soB = (float4*)(W + o_soB);
        int* stA = (int*)(W + o_stA);
        int* stB = (int*)(W + o_stB);
        int* cuA = (int*)(W + o_cuA);
        int* cuB = (int*)(W + o_cuB);
        float* part = (float*)(W + o_part);

        const int nPts = Ni + Nj;
        const int nmax = ((GA3 > GB3) ? GA3 : GB3) + 1;

        grid_zero<<<(nmax + 255) / 256, 256, 0, stream>>>(stA, GA3 + 1, stB, GB3 + 1, part);
        grid_count<<<(nPts + 255) / 256, 256, 0, stream>>>(
            coord_j, Nj, GA, stA, coord_i, Ni, GB, stB);
        grid_scan<<<2, 256, 0, stream>>>(stA, GA3, cuA, stB, GB3, cuB);
        grid_scatter<<<(nPts + 255) / 256, 256, 0, stream>>>(
            coord_j, Nj, GA, cuA, soA, coord_i, Ni, GB, cuB, soB);

        const int nQ = Ni + Nj;
        const int nblk = (nQ * 8 + 255) / 256;
        knnloss<<<nblk, 256, 0, stream>>>(
            feat_i, Ni, feat_j, Nj,
            soA, stA, GA, soB, stB, GB,
            0.5f / (float)Ni, 0.5f / (float)Nj, part);
        final_sum<<<1, 64, 0, stream>>>(part, out);
    } else {
        hipMemsetAsync(out, 0, sizeof(float), stream);
        const int waves0 = (Ni + 7) / 8;
        const int B0 = (waves0 + WPB - 1) / WPB;
        const int waves1 = (Nj + 3) / 4;
        const int B1 = (waves1 + WPB - 1) / WPB;
        brute_fused<<<B0 + B1, 256, 0, stream>>>(
            coord_i, feat_i, Ni, coord_j, feat_j, Nj,
            0.5f / (float)Ni, 0.5f / (float)Nj, B0, B1, out);
    }
}

// Round 14
// 49.563 us; speedup vs baseline: 1.8457x; 1.2301x over previous
//
#include <hip/hip_runtime.h>
#include <math.h>

#define KMASK 0xFFFF8000u
#define IMASK 0x7FFFu

__device__ __forceinline__ float wave_reduce_sum(float v) {
    #pragma unroll
    for (int off = 32; off >= 1; off >>= 1) v += __shfl_xor(v, off, 64);
    return v;
}

__device__ __forceinline__ unsigned wave_min_u32(unsigned v) {
    #pragma unroll
    for (int off = 32; off >= 1; off >>= 1) {
        unsigned o = (unsigned)__shfl_xor((int)v, off, 64);
        v = (o < v) ? o : v;
    }
    return v;
}

// reductions over aligned 8-lane group (xor 4,2,1 stays in-group)
__device__ __forceinline__ unsigned gmin8(unsigned v) {
    #pragma unroll
    for (int off = 4; off >= 1; off >>= 1) {
        unsigned o = (unsigned)__shfl_xor((int)v, off, 64);
        v = (o < v) ? o : v;
    }
    return v;
}
__device__ __forceinline__ float gsum8(float v) {
    #pragma unroll
    for (int off = 4; off >= 1; off >>= 1) v += __shfl_xor(v, off, 64);
    return v;
}

// sorted ascending insert of (key,value) into 4-element lists
__device__ __forceinline__ void insert4kv(unsigned k, unsigned v,
                                          unsigned (&bk)[4], unsigned (&bv)[4]) {
    const bool c0 = k < bk[0], c1 = k < bk[1], c2 = k < bk[2], c3 = k < bk[3];
    bk[3] = c2 ? bk[2] : (c3 ? k : bk[3]);
    bv[3] = c2 ? bv[2] : (c3 ? v : bv[3]);
    bk[2] = c1 ? bk[1] : (c2 ? k : bk[2]);
    bv[2] = c1 ? bv[1] : (c2 ? v : bv[2]);
    bk[1] = c0 ? bk[0] : (c1 ? k : bk[1]);
    bv[1] = c0 ? bv[0] : (c1 ? v : bv[1]);
    bk[0] = c0 ? k : bk[0];
    bv[0] = c0 ? v : bv[0];
}

__device__ __forceinline__ int cell_of(float x, int G) {
    int c = (int)(x * (float)G);
    return (c < 0) ? 0 : ((c >= G) ? G - 1 : c);
}

__device__ __forceinline__ float dot4(float4 a, float4 b) {
    return fmaf(a.w, b.w, fmaf(a.z, b.z, fmaf(a.y, b.y, a.x * b.x)));
}

// ============================ grid build (parallel) ============================

__global__ __launch_bounds__(256)
void grid_zero(int* __restrict__ stA, int nA, int* __restrict__ stB, int nB,
               float* __restrict__ out)
{
    const int t = blockIdx.x * 256 + threadIdx.x;
    if (t < nA) stA[t] = 0;
    if (t < nB) stB[t] = 0;
    if (t == 0) out[0] = 0.0f;
}

__global__ __launch_bounds__(256)
void grid_count(const float* __restrict__ cA, int nA, int GA, int* __restrict__ stA,
                const float* __restrict__ cB, int nB, int GB, int* __restrict__ stB)
{
    const int t = blockIdx.x * 256 + threadIdx.x;
    const float* c; int* s; int G; int p;
    if (t < nA)           { c = cA; s = stA; G = GA; p = t; }
    else if (t < nA + nB) { c = cB; s = stB; G = GB; p = t - nA; }
    else return;
    const int cx = cell_of(c[3*p], G), cy = cell_of(c[3*p+1], G), cz = cell_of(c[3*p+2], G);
    atomicAdd(&s[(cz * G + cy) * G + cx + 1], 1);
}

// in-place inclusive scan of s[0..n]; also writes cu[i] = s[i] (cell cursors)
__global__ __launch_bounds__(256)
void grid_scan(int* __restrict__ sA, int nA, int* __restrict__ cuA,
               int* __restrict__ sB, int nB, int* __restrict__ cuB)
{
    int* s  = blockIdx.x ? sB  : sA;
    int* cu = blockIdx.x ? cuB : cuA;
    const int n = blockIdx.x ? nB : nA;
    __shared__ int part[256];
    const int t = threadIdx.x;
    const int len = n + 1;
    const int chunk = (len + 255) >> 8;
    const int lo = t * chunk;
    const int hi = (lo + chunk < len) ? (lo + chunk) : len;
    int sum = 0;
    for (int i = lo; i < hi; ++i) sum += s[i];
    part[t] = sum;
    __syncthreads();
    for (int d = 1; d < 256; d <<= 1) {
        const int v = (t >= d) ? part[t - d] : 0;
        __syncthreads();
        part[t] += v;
        __syncthreads();
    }
    int run = (t > 0) ? part[t - 1] : 0;
    for (int i = lo; i < hi; ++i) {
        run += s[i];
        s[i] = run;
        if (i < n) cu[i] = run;
    }
}

// scatter: so[pos] = {x, y, z, bits(original_index)}
__global__ __launch_bounds__(256)
void grid_scatter(const float* __restrict__ cA, int nA, int GA, int* __restrict__ cuA,
                  float4* __restrict__ soA,
                  const float* __restrict__ cB, int nB, int GB, int* __restrict__ cuB,
                  float4* __restrict__ soB)
{
    const int t = blockIdx.x * 256 + threadIdx.x;
    const float* c; int* cu; float4* so; int G; int p;
    if (t < nA)           { c = cA; cu = cuA; so = soA; G = GA; p = t; }
    else if (t < nA + nB) { c = cB; cu = cuB; so = soB; G = GB; p = t - nA; }
    else return;
    const float x = c[3*p], y = c[3*p+1], z = c[3*p+2];
    const int cx = cell_of(x, G), cy = cell_of(y, G), cz = cell_of(z, G);
    const int pos = atomicAdd(&cu[(cz * G + cy) * G + cx], 1);
    so[pos] = make_float4(x, y, z, __uint_as_float((unsigned)p));
}

// ============= fused grid KNN + loss, 8 lanes/query, sorted order =============
// Chain: soq -> st(18, prefetched) -> so-sweep (2-wide batched) -> features.
// Original indices ride in so.w through (key,value) top-4 lists.

__global__ __launch_bounds__(256)
void knnloss(const float* __restrict__ fi, int Ni,
             const float* __restrict__ fj, int Nj,
             const float4* __restrict__ soA, const int* __restrict__ stA, int GA,
             const float4* __restrict__ soB, const int* __restrict__ stB, int GB,
             float sc0, float sc1, float* __restrict__ out)
{
    const int sub = threadIdx.x & 7;
    const int qid = (blockIdx.x * 256 + threadIdx.x) >> 3;
    float acc = 0.0f;

    if (qid < Ni + Nj) {
        const bool d0 = (qid < Ni);
        const int sq = d0 ? qid : qid - Ni;       // slot in own cloud's sorted array
        const float4* soq = d0 ? soB : soA;       // B = cloud i sorted, A = cloud j sorted
        const float4* so = d0 ? soA : soB;        // db = other cloud
        const int*    st = d0 ? stA : stB;
        const int      G = d0 ? GA  : GB;
        const int     nd = d0 ? Nj  : Ni;
        const float*  fd = d0 ? fj  : fi;
        const float scale = d0 ? sc0 : sc1;

        const float4 Q = soq[sq];                 // x,y,z,bits(orig idx)
        const unsigned p = __float_as_uint(Q.w);
        const float* fqp = (d0 ? fi : fj) + (size_t)p * 96;

        // hoisted q-feature fragment (depends only on Q)
        const float4* q4 = (const float4*)fqp;
        const float4 qa = q4[3*sub], qb = q4[3*sub+1], qc = q4[3*sub+2];

        const float qx = Q.x, qy = Q.y, qz = Q.z;
        const float h = 1.0f / (float)G;
        const int cx = cell_of(qx, G), cy = cell_of(qy, G), cz = cell_of(qz, G);
        unsigned nk[4], nv[4];

        // ---------- fast path: s = 1, 3x3 rows prefetched ----------
        {
            const int x0 = max(cx - 1, 0), x1 = min(cx + 1, G - 1);
            int csr[9], cer[9];
            #pragma unroll
            for (int dz = 0; dz < 3; ++dz) {
                #pragma unroll
                for (int dy = 0; dy < 3; ++dy) {
                    const int zz = cz + dz - 1, yy = cy + dy - 1;
                    const bool v = ((unsigned)zz < (unsigned)G) & ((unsigned)yy < (unsigned)G);
                    const int rb = v ? (zz * G + yy) * G : 0;
                    csr[dz*3+dy] = v ? st[rb + x0] : 0;
                    cer[dz*3+dy] = v ? st[rb + x1 + 1] : 0;
                }
            }
            unsigned bk[4] = {~0u, ~0u, ~0u, ~0u};
            unsigned bv[4] = {~0u, ~0u, ~0u, ~0u};
            #pragma unroll
            for (int r = 0; r < 9; ++r) {
                const int ce = cer[r];
                for (int cc = csr[r] + sub; cc < ce; cc += 16) {
                    // 2-wide batched loads: both issued before either insert
                    const float4 P0 = so[cc];
                    const int cc1 = cc + 8;
                    const bool v1 = (cc1 < ce);
                    float4 P1 = P0;
                    if (v1) P1 = so[cc1];
                    const float dx0 = P0.x - qx, dy0 = P0.y - qy, dz0 = P0.z - qz;
                    const float d20 = fmaf(dx0, dx0, fmaf(dy0, dy0, dz0 * dz0));
                    const unsigned k0 = (__float_as_uint(d20) & KMASK) | (unsigned)cc;
                    insert4kv(k0, __float_as_uint(P0.w), bk, bv);
                    const float dx1 = P1.x - qx, dy1 = P1.y - qy, dz1 = P1.z - qz;
                    const float d21 = fmaf(dx1, dx1, fmaf(dy1, dy1, dz1 * dz1));
                    unsigned k1 = (__float_as_uint(d21) & KMASK) | (unsigned)cc1;
                    if (!v1) k1 = ~0u;                  // never displaces a real entry
                    insert4kv(k1, __float_as_uint(P1.w), bk, bv);
                }
            }
            unsigned k0 = bk[0], k1 = bk[1], k2 = bk[2], k3 = bk[3];
            unsigned v0 = bv[0], v1 = bv[1], v2 = bv[2], v3 = bv[3];
            #pragma unroll
            for (int r = 0; r < 4; ++r) {
                const unsigned m = gmin8(k0);
                const bool win = (k0 == m);
                nv[r] = gmin8(win ? v0 : ~0u);
                nk[r] = m;
                k0 = win ? k1 : k0; v0 = win ? v1 : v0;
                k1 = win ? k2 : k1; v1 = win ? v2 : v1;
                k2 = win ? k3 : k2; v2 = win ? v3 : v2;
                k3 = win ? ~0u : k3;
            }
            const int y0 = max(cy - 1, 0), y1 = min(cy + 1, G - 1);
            const int z0 = max(cz - 1, 0), z1 = min(cz + 1, G - 1);
            float margin = 3.0e38f;
            if (x0 > 0)     margin = fminf(margin, qx - (float)x0 * h);
            if (x1 < G - 1) margin = fminf(margin, (float)(x1 + 1) * h - qx);
            if (y0 > 0)     margin = fminf(margin, qy - (float)y0 * h);
            if (y1 < G - 1) margin = fminf(margin, (float)(y1 + 1) * h - qy);
            if (z0 > 0)     margin = fminf(margin, qz - (float)z0 * h);
            if (z1 < G - 1) margin = fminf(margin, (float)(z1 + 1) * h - qz);
            const bool covered = (margin > 1.0e37f);
            const float kd = __uint_as_float(nk[3] & KMASK);   // NaN-bits if <4 found
            const bool ok = covered || (kd * 1.01f <= margin * margin);

            // ---------- slow path (rare): expanding box from s = 2 ----------
            if (!ok) {
                for (int s = 2; ; ++s) {
                    const int sx0 = max(cx - s, 0), sx1 = min(cx + s, G - 1);
                    const int sy0 = max(cy - s, 0), sy1 = min(cy + s, G - 1);
                    const int sz0 = max(cz - s, 0), sz1 = min(cz + s, G - 1);
                    unsigned b2k[4] = {~0u, ~0u, ~0u, ~0u};
                    unsigned b2v[4] = {~0u, ~0u, ~0u, ~0u};
                    for (int z = sz0; z <= sz1; ++z) {
                        for (int y = sy0; y <= sy1; ++y) {
                            const int rb = (z * G + y) * G;
                            const int cs = st[rb + sx0];
                            const int ce = st[rb + sx1 + 1];
                            for (int cc = cs + sub; cc < ce; cc += 8) {
                                const float4 P = so[cc];
                                const float dx = P.x - qx, dy = P.y - qy, dz = P.z - qz;
                                const float d2 = fmaf(dx, dx, fmaf(dy, dy, dz * dz));
                                const unsigned k =
                                    (__float_as_uint(d2) & KMASK) | (unsigned)cc;
                                insert4kv(k, __float_as_uint(P.w), b2k, b2v);
                            }
                        }
                    }
                    unsigned u0 = b2k[0], u1 = b2k[1], u2 = b2k[2], u3 = b2k[3];
                    unsigned w0 = b2v[0], w1 = b2v[1], w2 = b2v[2], w3 = b2v[3];
                    #pragma unroll
                    for (int r = 0; r < 4; ++r) {
                        const unsigned m = gmin8(u0);
                        const bool win = (u0 == m);
                        nv[r] = gmin8(win ? w0 : ~0u);
                        nk[r] = m;
                        u0 = win ? u1 : u0; w0 = win ? w1 : w0;
                        u1 = win ? u2 : u1; w1 = win ? w2 : w1;
                        u2 = win ? u3 : u2; w2 = win ? w3 : w2;
                        u3 = win ? ~0u : u3;
                    }
                    float mg = 3.0e38f;
                    if (sx0 > 0)     mg = fminf(mg, qx - (float)sx0 * h);
                    if (sx1 < G - 1) mg = fminf(mg, (float)(sx1 + 1) * h - qx);
                    if (sy0 > 0)     mg = fminf(mg, qy - (float)sy0 * h);
                    if (sy1 < G - 1) mg = fminf(mg, (float)(sy1 + 1) * h - qy);
                    if (sz0 > 0)     mg = fminf(mg, qz - (float)sz0 * h);
                    if (sz1 < G - 1) mg = fminf(mg, (float)(sz1 + 1) * h - qz);
                    const bool cov = (mg > 1.0e37f);
                    const float k2d = __uint_as_float(nk[3] & KMASK);
                    if (cov || (k2d * 1.01f <= mg * mg)) break;
                }
            }
        }

        // ---------- feature phase: all loads issued, then reductions ----------
        const unsigned nm1 = (unsigned)(nd - 1);
        const unsigned i0 = nv[0] < nm1 ? nv[0] : nm1;
        const unsigned i1 = nv[1] < nm1 ? nv[1] : nm1;
        const unsigned i2 = nv[2] < nm1 ? nv[2] : nm1;
        const unsigned i3 = nv[3] < nm1 ? nv[3] : nm1;

        const float4* f0 = (const float4*)(fd + (size_t)i0 * 96);
        const float4* f1 = (const float4*)(fd + (size_t)i1 * 96);
        const float4* f2 = (const float4*)(fd + (size_t)i2 * 96);
        const float4* f3 = (const float4*)(fd + (size_t)i3 * 96);
        const float4 a0 = f0[3*sub], b0 = f0[3*sub+1], c0 = f0[3*sub+2];
        const float4 a1 = f1[3*sub], b1 = f1[3*sub+1], c1 = f1[3*sub+2];
        const float4 a2 = f2[3*sub], b2 = f2[3*sub+1], c2 = f2[3*sub+2];
        const float4 a3 = f3[3*sub], b3 = f3[3*sub+1], c3 = f3[3*sub+2];

        const float ssq = gsum8(dot4(qa,qa) + dot4(qb,qb) + dot4(qc,qc));

        float sim[4];
        {
            const float dv = gsum8(dot4(qa,a0) + dot4(qb,b0) + dot4(qc,c0));
            const float sd = gsum8(dot4(a0,a0) + dot4(b0,b0) + dot4(c0,c0));
            sim[0] = dv * rsqrtf(fmaxf(ssq, 1e-24f) * fmaxf(sd, 1e-24f)) * 10.0f;
        }
        {
            const float dv = gsum8(dot4(qa,a1) + dot4(qb,b1) + dot4(qc,c1));
            const float sd = gsum8(dot4(a1,a1) + dot4(b1,b1) + dot4(c1,c1));
            sim[1] = dv * rsqrtf(fmaxf(ssq, 1e-24f) * fmaxf(sd, 1e-24f)) * 10.0f;
        }
        {
            const float dv = gsum8(dot4(qa,a2) + dot4(qb,b2) + dot4(qc,c2));
            const float sd = gsum8(dot4(a2,a2) + dot4(b2,b2) + dot4(c2,c2));
            sim[2] = dv * rsqrtf(fmaxf(ssq, 1e-24f) * fmaxf(sd, 1e-24f)) * 10.0f;
        }
        {
            const float dv = gsum8(dot4(qa,a3) + dot4(qb,b3) + dot4(qc,c3));
            const float sd = gsum8(dot4(a3,a3) + dot4(b3,b3) + dot4(c3,c3));
            sim[3] = dv * rsqrtf(fmaxf(ssq, 1e-24f) * fmaxf(sd, 1e-24f)) * 10.0f;
        }

        const float m = fmaxf(fmaxf(sim[0], sim[1]), fmaxf(sim[2], sim[3]));
        const float e0 = __expf(sim[0] - m), e1 = __expf(sim[1] - m);
        const float e2 = __expf(sim[2] - m), e3 = __expf(sim[3] - m);
        const float ssum = e0 + e1 + e2 + e3;
        const float inv = 1.0f / ssum;
        const float p2 = (e0*e0 + e1*e1 + e2*e2 + e3*e3) * inv * inv;
        if (sub == 0) acc = -__logf(p2 + 1e-12f) * scale;
    }

    // block-level reduction -> one atomic per block
    acc = wave_reduce_sum(acc);
    __shared__ float red[4];
    if ((threadIdx.x & 63) == 0) red[threadIdx.x >> 6] = acc;
    __syncthreads();
    if (threadIdx.x == 0) atomicAdd(out, red[0] + red[1] + red[2] + red[3]);
}

// ============================ brute fallback ============================

#define WPB 4
__device__ __forceinline__ void insert4u(unsigned k, unsigned (&b)[4]) {
    const bool c0 = k < b[0], c1 = k < b[1], c2 = k < b[2], c3 = k < b[3];
    b[3] = c2 ? b[2] : (c3 ? k : b[3]);
    b[2] = c1 ? b[1] : (c2 ? k : b[2]);
    b[1] = c0 ? b[0] : (c1 ? k : b[1]);
    b[0] = c0 ? k : b[0];
}

template<int QPW>
__device__ __forceinline__ void brute_dir(
    const float* __restrict__ cq, const float* __restrict__ fq, int Nq,
    const float* __restrict__ cd, const float* __restrict__ fd, int Nd,
    float scale, float* __restrict__ out, int blk)
{
    const int lane = threadIdx.x & 63;
    const int widx = threadIdx.x >> 6;
    int qbase = (blk * WPB + widx) * QPW;
    if (qbase >= Nq) return;
    qbase = __builtin_amdgcn_readfirstlane(qbase);

    float qx[QPW], qy[QPW], qz[QPW];
    #pragma unroll
    for (int q = 0; q < QPW; ++q) {
        const int qi = (qbase + q < Nq) ? (qbase + q) : (Nq - 1);
        qx[q] = cq[qi*3]; qy[q] = cq[qi*3+1]; qz[q] = cq[qi*3+2];
    }
    unsigned bk[QPW][4];
    #pragma unroll
    for (int q = 0; q < QPW; ++q) {
        #pragma unroll
        for (int k = 0; k < 4; ++k) bk[q][k] = ~0u;
    }
    for (int base = 0; base < Nd; base += 64) {
        const int p = base + lane;
        const int cp = (p < Nd) ? p : (Nd - 1);
        const float px = cd[cp*3], py = cd[cp*3+1], pz = cd[cp*3+2];
        #pragma unroll
        for (int q = 0; q < QPW; ++q) {
            const float dx = px - qx[q], dy = py - qy[q], dz = pz - qz[q];
            const float d2 = dx*dx + dy*dy + dz*dz;
            unsigned k = (__float_as_uint(d2) & KMASK) | (unsigned)p;
            if (p >= Nd) k = ~0u;
            insert4u(k, bk[q]);
        }
    }
    float wacc = 0.0f;
    #pragma unroll
    for (int q = 0; q < QPW; ++q) {
        if (qbase + q >= Nq) break;
        unsigned t0 = bk[q][0], t1 = bk[q][1], t2 = bk[q][2], t3 = bk[q][3];
        int ni_[4];
        #pragma unroll
        for (int k = 0; k < 4; ++k) {
            const unsigned m = wave_min_u32(t0);
            ni_[k] = (int)(m & IMASK);
            const bool win = (t0 == m);
            t0 = win ? t1 : t0; t1 = win ? t2 : t1; t2 = win ? t3 : t2; t3 = win ? ~0u : t3;
        }
        const float* fqp = fq + (size_t)(qbase + q) * 96;
        const float qf0 = fqp[lane];
        const float qf1 = (lane < 32) ? fqp[64 + lane] : 0.0f;
        const float ssq = wave_reduce_sum(qf0*qf0 + qf1*qf1);
        float sim[4];
        #pragma unroll
        for (int k = 0; k < 4; ++k) {
            const float* fdp = fd + (size_t)ni_[k] * 96;
            const float df0 = fdp[lane];
            const float df1 = (lane < 32) ? fdp[64 + lane] : 0.0f;
            const float dotv = wave_reduce_sum(qf0*df0 + qf1*df1);
            const float ssd = wave_reduce_sum(df0*df0 + df1*df1);
            sim[k] = dotv * rsqrtf(fmaxf(ssq, 1e-24f) * fmaxf(ssd, 1e-24f)) * 10.0f;
        }
        const float m = fmaxf(fmaxf(sim[0], sim[1]), fmaxf(sim[2], sim[3]));
        const float e0 = __expf(sim[0]-m), e1 = __expf(sim[1]-m);
        const float e2 = __expf(sim[2]-m), e3 = __expf(sim[3]-m);
        const float ssum = e0+e1+e2+e3;
        const float inv = 1.0f/ssum;
        const float p2 = (e0*e0+e1*e1+e2*e2+e3*e3)*inv*inv;
        wacc += -__logf(p2 + 1e-12f);
    }
    if (lane == 0) atomicAdd(out, wacc * scale);
}

__global__ __launch_bounds__(256)
void brute_fused(const float* __restrict__ ci, const float* __restrict__ fi, int Ni,
                 const float* __restrict__ cj, const float* __restrict__ fj, int Nj,
                 float s0, float s1, int B0, int B1, float* __restrict__ out)
{
    const int bid = (int)blockIdx.x;
    const int bmin = (B0 < B1) ? B0 : B1;
    int dir, blk;
    if (bid < 2 * bmin) { dir = bid & 1; blk = bid >> 1; }
    else { dir = (B0 > B1) ? 0 : 1; blk = bid - bmin; }
    if (dir == 0) brute_dir<8>(ci, fi, Ni, cj, fj, Nj, s0, out, blk);
    else          brute_dir<4>(cj, fj, Nj, ci, fi, Ni, s1, out, blk);
}

// ============================ launch ============================

extern "C" void kernel_launch(void* const* d_in, const int* in_sizes, int n_in,
                              void* d_out, int out_size, void* d_ws, size_t ws_size,
                              hipStream_t stream) {
    const float* feat_i  = (const float*)d_in[0];
    const float* coord_i = (const float*)d_in[1];
    const float* feat_j  = (const float*)d_in[2];
    const float* coord_j = (const float*)d_in[3];
    const int Ni = in_sizes[0] / 96;
    const int Nj = in_sizes[2] / 96;
    float* out = (float*)d_out;

    auto gridfor = [](int n) {
        int g = (int)cbrtf((float)n / 4.5f);
        if (g < 2) g = 2;
        if (g > 28) g = 28;
        return g;
    };
    const int GA = gridfor(Nj), GB = gridfor(Ni);       // A: cloud j, B: cloud i
    const int GA3 = GA * GA * GA, GB3 = GB * GB * GB;

    size_t off = 0;
    auto alloc = [&](size_t bytes) { size_t o = off; off = (off + bytes + 15) & ~(size_t)15; return o; };
    const size_t o_soA  = alloc((size_t)Nj * 16);
    const size_t o_soB  = alloc((size_t)Ni * 16);
    const size_t o_stA  = alloc((size_t)(GA3 + 1) * 4);
    const size_t o_stB  = alloc((size_t)(GB3 + 1) * 4);
    const size_t o_cuA  = alloc((size_t)GA3 * 4);
    const size_t o_cuB  = alloc((size_t)GB3 * 4);

    if (ws_size >= off && Ni >= 16 && Nj >= 16 && Ni <= 32000 && Nj <= 32000) {
        char* W = (char*)d_ws;
        float4* soA = (float4*)(W + o_soA);
        float4* soB = (float4*)(W + o_soB);
        int* stA = (int*)(W + o_stA);
        int* stB = (int*)(W + o_stB);
        int* cuA = (int*)(W + o_cuA);
        int* cuB = (int*)(W + o_cuB);

        const int nPts = Ni + Nj;
        const int nmax = ((GA3 > GB3) ? GA3 : GB3) + 1;

        grid_zero<<<(nmax + 255) / 256, 256, 0, stream>>>(stA, GA3 + 1, stB, GB3 + 1, out);
        grid_count<<<(nPts + 255) / 256, 256, 0, stream>>>(
            coord_j, Nj, GA, stA, coord_i, Ni, GB, stB);
        grid_scan<<<2, 256, 0, stream>>>(stA, GA3, cuA, stB, GB3, cuB);
        grid_scatter<<<(nPts + 255) / 256, 256, 0, stream>>>(
            coord_j, Nj, GA, cuA, soA, coord_i, Ni, GB, cuB, soB);

        const int nQ = Ni + Nj;
        const int nblk = (nQ * 8 + 255) / 256;
        knnloss<<<nblk, 256, 0, stream>>>(
            feat_i, Ni, feat_j, Nj,
            soA, stA, GA, soB, stB, GB,
            0.5f / (float)Ni, 0.5f / (float)Nj, out);
    } else {
        hipMemsetAsync(out, 0, sizeof(float), stream);
        const int waves0 = (Ni + 7) / 8;
        const int B0 = (waves0 + WPB - 1) / WPB;
        const int waves1 = (Nj + 3) / 4;
        const int B1 = (waves1 + WPB - 1) / WPB;
        brute_fused<<<B0 + B1, 256, 0, stream>>>(
            coord_i, feat_i, Ni, coord_j, feat_j, Nj,
            0.5f / (float)Ni, 0.5f / (float)Nj, B0, B1, out);
    }
}